// Round 2
// baseline (117.639 us; speedup 1.0000x reference)
//
#include <hip/hip_runtime.h>
#include <hip/hip_bf16.h>

typedef __attribute__((ext_vector_type(8))) short bf16x8;
typedef __attribute__((ext_vector_type(4))) float f32x4;

#define CIN   128
#define COUT  256
#define NIMG  32
#define HWDIM 56
#define HPAD  58
#define KTOT  1152            // 9*128
#define HWIMG 3136            // 56*56
#define MTOT  100352          // 32*3136
#define BN    256             // spatial tile (GEMM N); BM = 256 = all couts
#define BK    32
#define NT    36              // K tiles of 32

__device__ __forceinline__ void gload16(const void* g, void* l) {
  __builtin_amdgcn_global_load_lds((const __attribute__((address_space(1))) void*)g,
                                   (__attribute__((address_space(3))) void*)l,
                                   16, 0, 0);
}

// ---------------- pre-pass 0: zero ONLY the halo of padded x --------------
// rows 0 & 57 full; cols 0 & 57 of rows 1..56. 116736 16B-chunks total.
__global__ __launch_bounds__(256)
void zero_halo(__hip_bfloat16* __restrict__ xp) {
  int idx = blockIdx.x * 256 + threadIdx.x;   // exactly 456*256 = 116736
  int n = idx / 3648;
  int r = idx - n * 3648;
  size_t base = (size_t)n * HPAD * HPAD * CIN;
  size_t off;
  if (r < 1856) {                 // top/bottom full rows (928 chunks each)
    int half = r / 928;
    int c = r - half * 928;
    off = base + (size_t)(half ? 57 : 0) * HPAD * CIN + (size_t)c * 8;
  } else {
    int r2 = r - 1856;            // 0..1791: rows 1..56, cols {0,57}, 16 chunks
    int h = 1 + (r2 >> 5);
    int rem = r2 & 31;
    int side = rem >> 4;
    int chunk = rem & 15;
    off = base + ((size_t)h * HPAD + (side ? 57 : 0)) * CIN + (size_t)chunk * 8;
  }
  int4 z; z.x = 0; z.y = 0; z.z = 0; z.w = 0;
  *reinterpret_cast<int4*>(xp + off) = z;
}

// ---------------- pre-pass 1: x NCHW f32 -> padded NHWC bf16 --------------
__global__ __launch_bounds__(256)
void prep_x(const float* __restrict__ x, __hip_bfloat16* __restrict__ xp) {
  __shared__ float tile[CIN * 57];
  const int nh = blockIdx.x;
  const int n = nh / HWDIM;
  const int h = nh - n * HWDIM;
  const int t = threadIdx.x;

  const float* src = x + (size_t)n * CIN * HWIMG + (size_t)h * HWDIM;
  for (int i = t; i < CIN * HWDIM; i += 256) {
    int c = i / HWDIM;
    int w = i - c * HWDIM;
    tile[c * 57 + w] = src[(size_t)c * HWIMG + w];
  }
  __syncthreads();

  __hip_bfloat16* dst = xp + (((size_t)n * HPAD + (h + 1)) * HPAD + 1) * CIN;
  for (int o = t; o < HWDIM * 64; o += 256) {
    int w = o >> 6;
    int c = (o & 63) * 2;
    __hip_bfloat162 pr;
    pr.x = __float2bfloat16(tile[c * 57 + w]);
    pr.y = __float2bfloat16(tile[(c + 1) * 57 + w]);
    *reinterpret_cast<__hip_bfloat162*>(dst + (size_t)w * CIN + c) = pr;
  }
}

// ---------------- pre-pass 2: weights -> sign, bf16, [cout][tap*128+cin] --
__global__ __launch_bounds__(256)
void prep_w(const float* __restrict__ wsrc, __hip_bfloat16* __restrict__ wt) {
  int o = blockIdx.x * 256 + threadIdx.x;
  if (o >= COUT * KTOT) return;
  int cout = o / KTOT;
  int r = o - cout * KTOT;
  int tap = r >> 7;
  int cin = r & 127;
  float v = wsrc[((size_t)cout * CIN + cin) * 9 + tap];
  float s = (v > 0.f) ? 1.f : ((v < 0.f) ? -1.f : 0.f);
  wt[o] = __float2bfloat16(s);
}

// ---------------- main: 256x256 tile, BK=32, triple-buffered pipeline -----
// Stage lead = 2 tiles; counted vmcnt(4) once per tile (never 0 in loop).
// Raw s_barrier (no compiler vmcnt(0) drain). setprio around MFMA clusters.
__global__ __launch_bounds__(512, 2)
void bconv8(const short* __restrict__ xp, const short* __restrict__ wt,
            const float* __restrict__ bias, float* __restrict__ out) {
  __shared__ short lw[3][COUT * BK];   // 3 x 16 KB (A: weights)
  __shared__ short lx[3][BN * BK];     // 3 x 16 KB (B: x)

  const int tid  = threadIdx.x;
  const int lane = tid & 63;
  const int wv   = tid >> 6;      // 0..7
  const int wm   = wv >> 2;       // 0..1 : cout half (128 rows)
  const int wn   = wv & 3;        // 0..3 : spatial quarter (64 cols)
  const int s0   = blockIdx.x * BN;

  // staging: 4 slots of 8 bf16 per 32-k row; 512 thr x 16B = 128 rows/round
  const int srow = tid >> 2;      // 0..127
  const int slot = tid & 3;

  int xbase[2];
#pragma unroll
  for (int r = 0; r < 2; ++r) {
    int m  = s0 + r * 128 + srow;
    int n  = m / HWIMG;
    int hw = m - n * HWIMG;
    int h  = hw / HWDIM;
    int w  = hw - h * HWDIM;
    xbase[r] = ((n * HPAD + h) * HPAD + w) * CIN + slot * 8;   // + tap/cin off
  }
  const int wbase = srow * KTOT + slot * 8;

  // wave-uniform LDS stage bases (shorts): rows (r*128 + wv*16)
#define LWDST(S, R) ((short*)&lw[(S)][((R) * 128 + wv * 16) * BK])
#define LXDST(S, R) ((short*)&lx[(S)][((R) * 128 + wv * 16) * BK])
#define XKO(T) (((((T) >> 2) / 3) * HPAD + (((T) >> 2) - (((T) >> 2) / 3) * 3)) * CIN + ((T) & 3) * 32)

  f32x4 acc[8][4] = {};

  // prologue: stage A(0), B(0), A(1), B(1); wait tile 0 landed (vmcnt 4)
#pragma unroll
  for (int r = 0; r < 2; ++r) gload16(wt + r * 128 * KTOT + wbase + 0 * BK, LWDST(0, r));
#pragma unroll
  for (int r = 0; r < 2; ++r) gload16(xp + xbase[r] + XKO(0), LXDST(0, r));
#pragma unroll
  for (int r = 0; r < 2; ++r) gload16(wt + r * 128 * KTOT + wbase + 1 * BK, LWDST(1, r));
#pragma unroll
  for (int r = 0; r < 2; ++r) gload16(xp + xbase[r] + XKO(1), LXDST(1, r));
  asm volatile("s_waitcnt vmcnt(4)" ::: "memory");
  __builtin_amdgcn_s_barrier();

  const int rlo = lane & 15;
  const int kq  = lane >> 4;      // 0..3 : 8-bf16 k-chunk

  int s = 0;                      // t % 3
  for (int t = 0; t < NT; ++t) {
    int s2 = s + 2; if (s2 >= 3) s2 -= 3;          // (t+2) % 3
    const short* A = &lw[s][0];
    const short* B = &lx[s][0];

    // ---- phase 1: quadrant mf 0..3 ----
    bf16x8 af[4], bx[4];
#pragma unroll
    for (int f = 0; f < 4; ++f)
      af[f] = *(const bf16x8*)&A[(wm * 128 + f * 16 + rlo) * BK + kq * 8];
#pragma unroll
    for (int f = 0; f < 4; ++f)
      bx[f] = *(const bf16x8*)&B[(wn * 64 + f * 16 + rlo) * BK + kq * 8];
    if (t + 2 < NT) {             // stage A(t+2) -> slot s2 (not read by t,t+1)
      const int ko = (t + 2) * BK;
#pragma unroll
      for (int r = 0; r < 2; ++r) gload16(wt + r * 128 * KTOT + wbase + ko, LWDST(s2, r));
    }
    __builtin_amdgcn_s_barrier();
    asm volatile("s_waitcnt lgkmcnt(0)" ::: "memory");
    __builtin_amdgcn_sched_barrier(0);
    __builtin_amdgcn_s_setprio(1);
#pragma unroll
    for (int mf = 0; mf < 4; ++mf)
#pragma unroll
      for (int nf = 0; nf < 4; ++nf)
        acc[mf][nf] = __builtin_amdgcn_mfma_f32_16x16x32_bf16(af[mf], bx[nf], acc[mf][nf], 0, 0, 0);
    __builtin_amdgcn_s_setprio(0);
    __builtin_amdgcn_s_barrier();

    // ---- phase 2: quadrant mf 4..7 (bx reused in registers) ----
#pragma unroll
    for (int f = 0; f < 4; ++f)
      af[f] = *(const bf16x8*)&A[(wm * 128 + 64 + f * 16 + rlo) * BK + kq * 8];
    if (t + 2 < NT) {             // stage B(t+2)
      const int xko = XKO(t + 2);
#pragma unroll
      for (int r = 0; r < 2; ++r) gload16(xp + xbase[r] + xko, LXDST(s2, r));
    }
    // counted vmcnt: forces tile t+1 landed, leaves this tile's 4 stages in flight
    if (t + 2 < NT) asm volatile("s_waitcnt vmcnt(4)" ::: "memory");
    else            asm volatile("s_waitcnt vmcnt(0)" ::: "memory");
    __builtin_amdgcn_s_barrier();
    asm volatile("s_waitcnt lgkmcnt(0)" ::: "memory");
    __builtin_amdgcn_sched_barrier(0);
    __builtin_amdgcn_s_setprio(1);
#pragma unroll
    for (int mf = 0; mf < 4; ++mf)
#pragma unroll
      for (int nf = 0; nf < 4; ++nf)
        acc[4 + mf][nf] = __builtin_amdgcn_mfma_f32_16x16x32_bf16(af[mf], bx[nf], acc[4 + mf][nf], 0, 0, 0);
    __builtin_amdgcn_s_setprio(0);
    __builtin_amdgcn_s_barrier();

    s = s + 1; if (s == 3) s = 0;
  }

  // epilogue: D row = cout, col = spatial m (m89-verified C/D layout)
  const int col = lane & 15;
  const int rg  = lane >> 4;
#pragma unroll
  for (int nf = 0; nf < 4; ++nf) {
    int m  = s0 + wn * 64 + nf * 16 + col;
    int n  = m / HWIMG;
    int hw = m - n * HWIMG;
    float* ob = out + (size_t)n * (COUT * HWIMG) + hw;
#pragma unroll
    for (int mf = 0; mf < 8; ++mf) {
      int c0 = wm * 128 + mf * 16 + rg * 4;
      const float4 bv = *reinterpret_cast<const float4*>(&bias[c0]);
      ob[(size_t)(c0 + 0) * HWIMG] = acc[mf][nf][0] + bv.x;
      ob[(size_t)(c0 + 1) * HWIMG] = acc[mf][nf][1] + bv.y;
      ob[(size_t)(c0 + 2) * HWIMG] = acc[mf][nf][2] + bv.z;
      ob[(size_t)(c0 + 3) * HWIMG] = acc[mf][nf][3] + bv.w;
    }
  }
#undef LWDST
#undef LXDST
#undef XKO
}

extern "C" void kernel_launch(void* const* d_in, const int* in_sizes, int n_in,
                              void* d_out, int out_size, void* d_ws, size_t ws_size,
                              hipStream_t stream) {
  const float* x = (const float*)d_in[0];
  const float* w = (const float*)d_in[1];
  const float* b = (const float*)d_in[2];
  float* out = (float*)d_out;

  const size_t xp_elems = (size_t)NIMG * HPAD * HPAD * CIN;
  __hip_bfloat16* xp = (__hip_bfloat16*)d_ws;
  __hip_bfloat16* wt = xp + xp_elems;

  zero_halo<<<456, 256, 0, stream>>>(xp);
  prep_x<<<NIMG * HWDIM, 256, 0, stream>>>(x, xp);
  prep_w<<<(COUT * KTOT + 255) / 256, 256, 0, stream>>>(w, wt);

  bconv8<<<MTOT / BN, 512, 0, stream>>>((const short*)xp, (const short*)wt, b, out);
}

// Round 3
// 98.421 us; speedup vs baseline: 1.1953x; 1.1953x over previous
//
#include <hip/hip_runtime.h>
#include <hip/hip_bf16.h>

typedef __attribute__((ext_vector_type(8))) short bf16x8;
typedef __attribute__((ext_vector_type(4))) float f32x4;

#define CIN   128
#define COUT  256
#define NIMG  32
#define HWDIM 56
#define HPAD  58
#define KTOT  1152            // 9*128
#define HWIMG 3136
#define MTOT  100352
#define BN    256             // spatial tile; all 256 couts per block
#define BK    64
#define NT    18              // K tiles of 64 (1152/64)
#define BSZA  (COUT * BK)     // 16384 shorts: A region size per buffer

__device__ __forceinline__ void gload16(const void* g, void* l) {
  __builtin_amdgcn_global_load_lds((const __attribute__((address_space(1))) void*)g,
                                   (__attribute__((address_space(3))) void*)l,
                                   16, 0, 0);
}

// ---------------- fused pre-pass: halo zero + x->NHWC bf16 + sign(w) ------
// grid: [0,1856) = 32 n x 58 h rows of padded x; [1856,3008) = weight chunks.
__global__ __launch_bounds__(256)
void prep_all(const float* __restrict__ x, const float* __restrict__ w,
              __hip_bfloat16* __restrict__ xp, __hip_bfloat16* __restrict__ wt) {
  __shared__ float tile[CIN * 57];
  const int bid = blockIdx.x;
  const int t = threadIdx.x;
  if (bid < NIMG * HPAD) {
    const int n = bid / HPAD;
    const int h = bid - n * HPAD;
    __hip_bfloat16* dstrow = xp + ((size_t)n * HPAD + h) * HPAD * CIN;
    int4 z; z.x = 0; z.y = 0; z.z = 0; z.w = 0;
    if (h == 0 || h == HPAD - 1) {          // full halo row: 58*128 bf16
      for (int i = t; i < (HPAD * CIN) / 8; i += 256)
        reinterpret_cast<int4*>(dstrow)[i] = z;
      return;
    }
    // interior row: load x[n][:][h-1][:] into LDS (transposed, padded stride)
    const float* src = x + (size_t)n * CIN * HWIMG + (size_t)(h - 1) * HWDIM;
    for (int i = t; i < CIN * HWDIM; i += 256) {
      int c = i / HWDIM;
      int wd = i - c * HWDIM;
      tile[c * 57 + wd] = src[(size_t)c * HWIMG + wd];
    }
    if (t < 32) {                            // halo cols 0 and 57 of this row
      int side = t >> 4;
      reinterpret_cast<int4*>(dstrow + (side ? (HPAD - 1) : 0) * CIN)[t & 15] = z;
    }
    __syncthreads();
    __hip_bfloat16* dst = dstrow + CIN;      // col 1
    for (int o = t; o < HWDIM * 64; o += 256) {
      int wd = o >> 6;
      int c = (o & 63) * 2;
      __hip_bfloat162 pr;
      pr.x = __float2bfloat16(tile[c * 57 + wd]);
      pr.y = __float2bfloat16(tile[(c + 1) * 57 + wd]);
      *reinterpret_cast<__hip_bfloat162*>(dst + (size_t)wd * CIN + c) = pr;
    }
  } else {
    int o = (bid - NIMG * HPAD) * 256 + t;   // exactly COUT*KTOT total
    int cout = o / KTOT;
    int r = o - cout * KTOT;
    int tap = r >> 7;
    int cin = r & 127;
    float v = w[((size_t)cout * CIN + cin) * 9 + tap];
    wt[o] = __float2bfloat16(v > 0.f ? 1.f : (v < 0.f ? -1.f : 0.f));
  }
}

// ---------------- main: 256x256, BK=64, 4-phase m201-style pipeline -------
__global__ __launch_bounds__(512, 2)
void bconv(const short* __restrict__ xp, const short* __restrict__ wt,
           const float* __restrict__ bias, float* __restrict__ out) {
  __shared__ short lds[2][2 * BSZA];   // per buf: A [256][64] then B [256][64]

  const int tid  = threadIdx.x;
  const int lane = tid & 63;
  const int wv   = tid >> 6;       // 0..7
  const int wm   = wv >> 2;        // 0,1 : 32-row half of each 64-row strip
  const int wn   = wv & 3;         // 0..3 : 64-col spatial window
  const int s0   = blockIdx.x * BN;

  // staging: 64 rows/round, 8 x 16B slots per row; swizzled global source
  const int srow = tid >> 3;       // 0..63
  const int swz  = (tid & 7) ^ (srow & 7);

  int xb[2][2];
#pragma unroll
  for (int h = 0; h < 2; ++h)
#pragma unroll
    for (int r = 0; r < 2; ++r) {
      int m  = s0 + h * 128 + r * 64 + srow;
      int n  = m / HWIMG;
      int hw = m - n * HWIMG;
      int hh = hw / HWDIM;
      int ww = hw - hh * HWDIM;
      xb[h][r] = ((n * HPAD + hh) * HPAD + ww) * CIN + swz * 8;
    }
  const int wb = srow * KTOT + swz * 8;

#define STAGE_A(C, H, R, KO) \
  gload16(wt + ((H) * 128 + (R) * 64) * KTOT + wb + (KO), \
          &lds[C][(((H) * 128 + (R) * 64) + wv * 8) * BK])
#define STAGE_B(C, H, R, XKO) \
  gload16(xp + xb[H][R] + (XKO), \
          &lds[C][BSZA + (((H) * 128 + (R) * 64) + wv * 8) * BK])

  const int rlo = lane & 15;
  const int kq  = lane >> 4;       // 0..3
  const int swr = rlo & 7;

  f32x4 acc[8][4] = {};
  bf16x8 bx[4][2], af[2][2];

#define AF_LOAD(Q) \
  _Pragma("unroll") for (int f = 0; f < 2; ++f) \
  _Pragma("unroll") for (int kk = 0; kk < 2; ++kk) \
    af[f][kk] = *(const bf16x8*)&A[((Q) * 64 + wm * 32 + f * 16 + rlo) * BK + ((kk * 4 + kq) ^ swr) * 8];

#define MFMA_CLUSTER(Q) \
  __builtin_amdgcn_s_barrier(); \
  asm volatile("s_waitcnt lgkmcnt(0)" ::: "memory"); \
  __builtin_amdgcn_sched_barrier(0); \
  __builtin_amdgcn_s_setprio(1); \
  _Pragma("unroll") for (int f = 0; f < 2; ++f) \
  _Pragma("unroll") for (int nf = 0; nf < 4; ++nf) \
  _Pragma("unroll") for (int kk = 0; kk < 2; ++kk) \
    acc[2 * (Q) + f][nf] = __builtin_amdgcn_mfma_f32_16x16x32_bf16(af[f][kk], bx[nf][kk], acc[2 * (Q) + f][nf], 0, 0, 0); \
  __builtin_amdgcn_s_setprio(0);

  // prologue: stage tile 0 fully into buf 0 (tap 0, cin 0..63 -> xko = 0)
  STAGE_B(0, 0, 0, 0); STAGE_B(0, 0, 1, 0);
  STAGE_B(0, 1, 0, 0); STAGE_B(0, 1, 1, 0);
  STAGE_A(0, 0, 0, 0); STAGE_A(0, 0, 1, 0);
  STAGE_A(0, 1, 0, 0); STAGE_A(0, 1, 1, 0);
  asm volatile("s_waitcnt vmcnt(0)" ::: "memory");
  __builtin_amdgcn_s_barrier();

  for (int t = 0; t < NT; ++t) {
    const int c  = t & 1;
    const int cn = c ^ 1;
    const short* A = &lds[c][0];
    const short* B = &lds[c][BSZA];
    const bool st = (t + 1 < NT);
    // next-tile global offsets
    const int t1   = t + 1;
    const int tap1 = t1 >> 1;
    const int kh1  = tap1 / 3;
    const int kw1  = tap1 - kh1 * 3;
    const int xko1 = (kh1 * HPAD + kw1) * CIN + (t1 & 1) * BK;
    const int ko1  = t1 * BK;

    // ---- phase 0: bx full-tile + af strip 0; stage B(t+1) h0 ----
#pragma unroll
    for (int nf = 0; nf < 4; ++nf)
#pragma unroll
      for (int kk = 0; kk < 2; ++kk)
        bx[nf][kk] = *(const bf16x8*)&B[(wn * 64 + nf * 16 + rlo) * BK + ((kk * 4 + kq) ^ swr) * 8];
    AF_LOAD(0)
    if (st) { STAGE_B(cn, 0, 0, xko1); STAGE_B(cn, 0, 1, xko1); }
    MFMA_CLUSTER(0)
    __builtin_amdgcn_s_barrier();

    // ---- phase 1: af strip 1; stage B(t+1) h1; vmcnt(4) guards A(t) h1 ----
    AF_LOAD(1)
    if (st) { STAGE_B(cn, 1, 0, xko1); STAGE_B(cn, 1, 1, xko1); }
    MFMA_CLUSTER(1)
    if (st) asm volatile("s_waitcnt vmcnt(4)" ::: "memory");
    else    asm volatile("s_waitcnt vmcnt(0)" ::: "memory");
    __builtin_amdgcn_s_barrier();

    // ---- phase 2: af strip 2; stage A(t+1) h0 ----
    AF_LOAD(2)
    if (st) { STAGE_A(cn, 0, 0, ko1); STAGE_A(cn, 0, 1, ko1); }
    MFMA_CLUSTER(2)
    __builtin_amdgcn_s_barrier();

    // ---- phase 3: af strip 3; stage A(t+1) h1; vmcnt(2) guards B(t+1)+A(t+1)h0 ----
    AF_LOAD(3)
    if (st) { STAGE_A(cn, 1, 0, ko1); STAGE_A(cn, 1, 1, ko1); }
    MFMA_CLUSTER(3)
    if (st) asm volatile("s_waitcnt vmcnt(2)" ::: "memory");
    __builtin_amdgcn_s_barrier();
  }

  // epilogue: D row = cout (A rows), col = spatial m (B rows)
  const int col = lane & 15;
  const int rg  = lane >> 4;
#pragma unroll
  for (int nf = 0; nf < 4; ++nf) {
    int m  = s0 + wn * 64 + nf * 16 + col;
    int n  = m / HWIMG;
    int hw = m - n * HWIMG;
    float* ob = out + (size_t)n * (COUT * HWIMG) + hw;
#pragma unroll
    for (int mi = 0; mi < 8; ++mi) {
      int c0 = (mi >> 1) * 64 + wm * 32 + (mi & 1) * 16 + rg * 4;
      const float4 bv = *reinterpret_cast<const float4*>(&bias[c0]);
      ob[(size_t)(c0 + 0) * HWIMG] = acc[mi][nf][0] + bv.x;
      ob[(size_t)(c0 + 1) * HWIMG] = acc[mi][nf][1] + bv.y;
      ob[(size_t)(c0 + 2) * HWIMG] = acc[mi][nf][2] + bv.z;
      ob[(size_t)(c0 + 3) * HWIMG] = acc[mi][nf][3] + bv.w;
    }
  }
#undef STAGE_A
#undef STAGE_B
#undef AF_LOAD
#undef MFMA_CLUSTER
}

extern "C" void kernel_launch(void* const* d_in, const int* in_sizes, int n_in,
                              void* d_out, int out_size, void* d_ws, size_t ws_size,
                              hipStream_t stream) {
  const float* x = (const float*)d_in[0];
  const float* w = (const float*)d_in[1];
  const float* b = (const float*)d_in[2];
  float* out = (float*)d_out;

  const size_t xp_elems = (size_t)NIMG * HPAD * HPAD * CIN;
  __hip_bfloat16* xp = (__hip_bfloat16*)d_ws;
  __hip_bfloat16* wt = xp + xp_elems;

  prep_all<<<NIMG * HPAD + (COUT * KTOT) / 256, 256, 0, stream>>>(x, w, xp, wt);
  bconv<<<MTOT / BN, 512, 0, stream>>>((const short*)xp, (const short*)wt, b, out);
}